// Round 8
// baseline (173.739 us; speedup 1.0000x reference)
//
#include <hip/hip_runtime.h>

typedef _Float16 half8 __attribute__((ext_vector_type(8)));
typedef __fp16 fp16x2 __attribute__((ext_vector_type(2)));
typedef float f32x4 __attribute__((ext_vector_type(4)));
typedef float f32x16 __attribute__((ext_vector_type(16)));
typedef unsigned int u32;
typedef unsigned short u16;

#define NB 4
#define NC 128
#define NN 4096
#define THR 8.0f

__device__ __forceinline__ void gload16(const void* g, void* l) {
    __builtin_amdgcn_global_load_lds(
        (const __attribute__((address_space(1))) u32*)g,
        (__attribute__((address_space(3))) u32*)l, 16, 0, 0);
}
__device__ __forceinline__ float h2f_u(u32 u) {
    u16 us = (u16)u;
    _Float16 h;
    __builtin_memcpy(&h, &us, 2);
    return (float)h;
}
__device__ __forceinline__ u16 f2h_u(float f) {
    _Float16 h = (_Float16)f;
    u16 us;
    __builtin_memcpy(&us, &h, 2);
    return us;
}
__device__ __forceinline__ float exp2_fast(float x) {
#if __has_builtin(__builtin_amdgcn_exp2f)
    return __builtin_amdgcn_exp2f(x);
#else
    return exp2f(x);
#endif
}
__device__ __forceinline__ int xs_addr(int c, int n) {
    return ((c << 8) + (n << 2)) ^ (((c >> 3) & 1) << 6);
}

// ---------------------------------------------------------------------------
// Kernel 1: QKV projection via fp16 MFMA (unchanged; works).
// ---------------------------------------------------------------------------
__global__ __launch_bounds__(512, 2) void qkv_proj_kernel(
    const float* __restrict__ x,
    const float* __restrict__ wq, const float* __restrict__ bq,
    const float* __restrict__ wk, const float* __restrict__ bk,
    const float* __restrict__ wv, const float* __restrict__ bv,
    _Float16* __restrict__ Qb, _Float16* __restrict__ Kb, _Float16* __restrict__ Vt)
{
    const int tid  = threadIdx.x;
    const int b    = blockIdx.x >> 6;
    const int n0   = (blockIdx.x & 63) << 6;
    const int lane = tid & 63;
    const int wave = __builtin_amdgcn_readfirstlane(tid >> 6);
    const int l15  = lane & 15, lg = lane >> 4;
    const int obase = wave * 16;

    __shared__ __align__(16) unsigned char xsm[32768];

    #pragma unroll
    for (int kk = 0; kk < 4; ++kk) {
        int g = kk * 512 + tid;
        int c = g >> 4, n4 = (g & 15) << 2;
        *(float4*)(xsm + xs_addr(c, n4)) = *(const float4*)(x + (size_t)(b * NC + c) * NN + n0 + n4);
    }
    __syncthreads();

    half8 bx[4][4];
    #pragma unroll
    for (int ct2 = 0; ct2 < 4; ++ct2) {
        int n = ct2 * 16 + l15;
        #pragma unroll
        for (int kc = 0; kc < 4; ++kc) {
            half8 h;
            #pragma unroll
            for (int j = 0; j < 8; ++j) {
                int c = kc * 32 + lg * 8 + j;
                h[j] = (_Float16)(*(const float*)(xsm + xs_addr(c, n)));
            }
            bx[ct2][kc] = h;
        }
    }

    #pragma unroll 1
    for (int mat = 0; mat < 3; ++mat) {
        const float* __restrict__ W  = (mat == 0) ? wq : ((mat == 1) ? wk : wv);
        const float* __restrict__ bi = (mat == 0) ? bq : ((mat == 1) ? bk : bv);

        half8 aw[4];
        #pragma unroll
        for (int kc = 0; kc < 4; ++kc) {
            const float* wp = W + (size_t)(obase + l15) * NC + kc * 32 + lg * 8;
            float4 w0 = *(const float4*)(wp);
            float4 w1 = *(const float4*)(wp + 4);
            half8 h;
            h[0] = (_Float16)w0.x; h[1] = (_Float16)w0.y; h[2] = (_Float16)w0.z; h[3] = (_Float16)w0.w;
            h[4] = (_Float16)w1.x; h[5] = (_Float16)w1.y; h[6] = (_Float16)w1.z; h[7] = (_Float16)w1.w;
            aw[kc] = h;
        }
        float bvv[4];
        #pragma unroll
        for (int r = 0; r < 4; ++r) bvv[r] = bi[obase + lg * 4 + r];

        f32x4 acc[4];
        #pragma unroll
        for (int ct2 = 0; ct2 < 4; ++ct2) acc[ct2] = (f32x4){0.f, 0.f, 0.f, 0.f};
        #pragma unroll
        for (int kc = 0; kc < 4; ++kc) {
            #pragma unroll
            for (int ct2 = 0; ct2 < 4; ++ct2)
                acc[ct2] = __builtin_amdgcn_mfma_f32_16x16x32_f16(aw[kc], bx[ct2][kc], acc[ct2], 0, 0, 0);
        }

        if (mat < 2) {
            _Float16* dst = (mat == 0) ? Qb : Kb;
            #pragma unroll
            for (int ct2 = 0; ct2 < 4; ++ct2) {
                int n = n0 + ct2 * 16 + l15;
                #pragma unroll
                for (int r = 0; r < 4; ++r)
                    dst[(size_t)(b * NN + n) * NC + obase + lg * 4 + r] = (_Float16)(acc[ct2][r] + bvv[r]);
            }
        } else {
            #pragma unroll
            for (int ct2 = 0; ct2 < 4; ++ct2) {
                int n = n0 + ct2 * 16 + l15;
                #pragma unroll
                for (int r = 0; r < 4; ++r)
                    Vt[(size_t)(b * NC + obase + lg * 4 + r) * NN + n] = (_Float16)(acc[ct2][r] + bvv[r]);
            }
        }
    }
}

// ---------------------------------------------------------------------------
// Kernel 2: flash attention, 32x32x16 MFMA, 64 q-rows per wave (2 q-tiles,
// read:MFMA = 1:2), kv-split S=8 -> 512 blocks = 2 blocks/CU = 2 waves/SIMD
// (VGPR ~244 <= 256). Double-buffered LDS + counted vmcnt + raw s_barrier.
// K tile: 4-bit XOR swizzle (16 slots/row) -> conflict-free reads.
// Normalized fp16 partials.
// ---------------------------------------------------------------------------
__global__ __launch_bounds__(256, 2) void attn_kernel(
    const _Float16* __restrict__ Qb, const _Float16* __restrict__ Kb,
    const _Float16* __restrict__ Vt, float* __restrict__ out,
    u16* __restrict__ parts, float* __restrict__ statM, float* __restrict__ statL,
    int lg2S)
{
    const int S = 1 << lg2S;
    const int tid = threadIdx.x;
    const int cpx = gridDim.x >> 3;
    const int lin = (blockIdx.x & 7) * cpx + (blockIdx.x >> 3);
    const int qt   = lin & 15;             // 16 q-tiles of 256
    const int rest = lin >> 4;             // = b * S + sp
    const int sp = rest & (S - 1);
    const int b  = rest >> lg2S;

    const int n0    = qt << 8;             // 256 q per block
    const int kvlen = NN >> lg2S;
    const int kv0   = sp * kvlen;
    const int iters = kvlen >> 6;

    const int lane = tid & 63;
    const int wave = __builtin_amdgcn_readfirstlane(tid >> 6);
    const int l31 = lane & 31, hi = lane >> 5;
    const int s7 = l31 & 7;
    const int s15 = l31 & 15;

    // double buffer: buf = (it&1)<<15. Within buf: K [0,16K), V [16K,32K).
    __shared__ __align__(16) unsigned char smem[65536];

    // ---- staging source offsets (linear LDS dest; inverse of layout map) ----
    int kgo[4], vgo[4], klds[4];
    #pragma unroll
    for (int j = 0; j < 4; ++j) {
        int i = (wave * 4 + j) * 64 + lane;          // chunk 0..1023 (16B units)
        int lam = i >> 4, slot = i & 15;
        int cc = slot ^ (lam & 15);                  // 4-bit XOR swizzle
        int kv = (lam & 51) | ((lam & 4) << 1) | ((lam & 8) >> 1);  // swap bits 2,3
        kgo[j] = kv * NC + cc * 8;
        int c = i >> 3, s2 = i & 7;
        vgo[j] = c * NN + ((s2 ^ (c & 7)) << 3);
        klds[j] = (wave * 4 + j) * 1024;
    }
    const _Float16* Kt0 = Kb + ((size_t)b * NN + kv0) * NC;
    const _Float16* Vt0 = Vt + (size_t)b * NC * NN + kv0;

    // ---- fragment read offsets ----
    int koff[8];
    #pragma unroll
    for (int kc = 0; kc < 8; ++kc) {
        int cc = kc * 2 + hi;
        koff[kc] = l31 * 256 + ((cc ^ s15) << 4);
    }
    int voff[4];
    #pragma unroll
    for (int ks = 0; ks < 4; ++ks) {
        int cc2 = ks * 2 + hi;
        voff[ks] = 16384 + l31 * 128 + ((cc2 ^ s7) << 4);
    }

    auto STAGE = [&](int t, int bb) {
        const _Float16* Kp = Kt0 + (size_t)t * 64 * NC;
        const _Float16* Vp = Vt0 + t * 64;
        #pragma unroll
        for (int j = 0; j < 4; ++j) {
            gload16(Kp + kgo[j], smem + bb + klds[j]);
            gload16(Vp + vgo[j], smem + bb + 16384 + klds[j]);
        }
    };

    // ---- prologue: Q frags first (oldest vmem), then tiles 0 and 1 ----
    half8 aq0[8], aq1[8];
    {
        const _Float16* qp0 = Qb + (size_t)(b * NN + n0 + wave * 64 + l31) * NC + hi * 8;
        const _Float16* qp1 = qp0 + (size_t)32 * NC;
        #pragma unroll
        for (int kc = 0; kc < 8; ++kc) {
            aq0[kc] = *(const half8*)(qp0 + kc * 16);
            aq1[kc] = *(const half8*)(qp1 + kc * 16);
        }
    }
    STAGE(0, 0);
    if (iters > 1) {
        STAGE(1, 32768);
        asm volatile("s_waitcnt vmcnt(8)" ::: "memory");  // q + tile0 landed; tile1 in flight
    } else {
        asm volatile("s_waitcnt vmcnt(0)" ::: "memory");
    }
    __builtin_amdgcn_s_barrier();

    float mrun0 = -3.0e38f, lsum0 = 0.f;
    float mrun1 = -3.0e38f, lsum1 = 0.f;
    f32x16 o0[4], o1[4];
    #pragma unroll
    for (int ct = 0; ct < 4; ++ct)
        #pragma unroll
        for (int r = 0; r < 16; ++r) { o0[ct][r] = 0.f; o1[ct][r] = 0.f; }

    const float L2E = 1.44269504f;

    for (int it = 0; it < iters; ++it) {
        const int bb = (it & 1) << 15;

        // ---- S = K Q^T : each K-frag feeds both q-tiles ----
        f32x16 s00, s01, s10, s11;
        #pragma unroll
        for (int r = 0; r < 16; ++r) { s00[r] = 0.f; s01[r] = 0.f; s10[r] = 0.f; s11[r] = 0.f; }
        __builtin_amdgcn_s_setprio(1);
        #pragma unroll
        for (int kc = 0; kc < 8; ++kc) {
            half8 k0 = *(const half8*)(smem + bb + koff[kc]);
            half8 k1 = *(const half8*)(smem + bb + koff[kc] + 8192);
            s00 = __builtin_amdgcn_mfma_f32_32x32x16_f16(k0, aq0[kc], s00, 0, 0, 0);
            s01 = __builtin_amdgcn_mfma_f32_32x32x16_f16(k1, aq0[kc], s01, 0, 0, 0);
            s10 = __builtin_amdgcn_mfma_f32_32x32x16_f16(k0, aq1[kc], s10, 0, 0, 0);
            s11 = __builtin_amdgcn_mfma_f32_32x32x16_f16(k1, aq1[kc], s11, 0, 0, 0);
        }
        __builtin_amdgcn_s_setprio(0);

        // ---- online softmax, in-lane; defer-rescale THR, per q-tile ----
        float tm0 = fmaxf(s00[0], s00[1]);
        float tm1 = fmaxf(s10[0], s10[1]);
        #pragma unroll
        for (int r = 2; r < 16; r += 2) {
            tm0 = fmaxf(tm0, fmaxf(s00[r], s00[r + 1]));
            tm1 = fmaxf(tm1, fmaxf(s10[r], s10[r + 1]));
        }
        #pragma unroll
        for (int r = 0; r < 16; r += 2) {
            tm0 = fmaxf(tm0, fmaxf(s01[r], s01[r + 1]));
            tm1 = fmaxf(tm1, fmaxf(s11[r], s11[r + 1]));
        }
        tm0 = fmaxf(tm0, __shfl_xor(tm0, 32, 64));
        tm1 = fmaxf(tm1, __shfl_xor(tm1, 32, 64));

        if (__any((tm0 > mrun0 + THR) || (tm1 > mrun1 + THR))) {
            float mn0 = fmaxf(mrun0, tm0);
            float mn1 = fmaxf(mrun1, tm1);
            float sc0 = __expf(mrun0 - mn0);
            float sc1 = __expf(mrun1 - mn1);
            #pragma unroll
            for (int ct = 0; ct < 4; ++ct)
                #pragma unroll
                for (int r = 0; r < 16; ++r) { o0[ct][r] *= sc0; o1[ct][r] *= sc1; }
            lsum0 *= sc0; lsum1 *= sc1;
            mrun0 = mn0; mrun1 = mn1;
        }
        float nm0 = -mrun0 * L2E, nm1 = -mrun1 * L2E;
        float ps0 = 0.f, ps1 = 0.f;
        #pragma unroll
        for (int r = 0; r < 16; ++r) {
            s00[r] = exp2_fast(fmaf(s00[r], L2E, nm0));
            s01[r] = exp2_fast(fmaf(s01[r], L2E, nm0));
            s10[r] = exp2_fast(fmaf(s10[r], L2E, nm1));
            s11[r] = exp2_fast(fmaf(s11[r], L2E, nm1));
            ps0 += s00[r] + s01[r];
            ps1 += s10[r] + s11[r];
        }
        ps0 += __shfl_xor(ps0, 32, 64);
        ps1 += __shfl_xor(ps1, 32, 64);
        lsum0 += ps0; lsum1 += ps1;

        // ---- P -> A-frags, fully in-lane ----
        union H8 { fp16x2 h2[4]; half8 h8; };
        half8 pa0[4], pa1[4];
        {
            H8 a0, a1, a2, a3, b0, b1, b2, b3;
            #pragma unroll
            for (int t = 0; t < 4; ++t) {
                a0.h2[t] = __builtin_amdgcn_cvt_pkrtz(s00[2 * t],     s00[2 * t + 1]);
                a1.h2[t] = __builtin_amdgcn_cvt_pkrtz(s00[8 + 2 * t], s00[9 + 2 * t]);
                a2.h2[t] = __builtin_amdgcn_cvt_pkrtz(s01[2 * t],     s01[2 * t + 1]);
                a3.h2[t] = __builtin_amdgcn_cvt_pkrtz(s01[8 + 2 * t], s01[9 + 2 * t]);
                b0.h2[t] = __builtin_amdgcn_cvt_pkrtz(s10[2 * t],     s10[2 * t + 1]);
                b1.h2[t] = __builtin_amdgcn_cvt_pkrtz(s10[8 + 2 * t], s10[9 + 2 * t]);
                b2.h2[t] = __builtin_amdgcn_cvt_pkrtz(s11[2 * t],     s11[2 * t + 1]);
                b3.h2[t] = __builtin_amdgcn_cvt_pkrtz(s11[8 + 2 * t], s11[9 + 2 * t]);
            }
            pa0[0] = a0.h8; pa0[1] = a1.h8; pa0[2] = a2.h8; pa0[3] = a3.h8;
            pa1[0] = b0.h8; pa1[1] = b1.h8; pa1[2] = b2.h8; pa1[3] = b3.h8;
        }

        // ---- O += V^T P : each V-frag feeds both q-tiles ----
        __builtin_amdgcn_s_setprio(1);
        #pragma unroll
        for (int ks = 0; ks < 4; ++ks) {
            #pragma unroll
            for (int ct = 0; ct < 4; ++ct) {
                half8 vf = *(const half8*)(smem + bb + voff[ks] + ct * 4096);
                o0[ct] = __builtin_amdgcn_mfma_f32_32x32x16_f16(vf, pa0[ks], o0[ct], 0, 0, 0);
                o1[ct] = __builtin_amdgcn_mfma_f32_32x32x16_f16(vf, pa1[ks], o1[ct], 0, 0, 0);
            }
        }
        __builtin_amdgcn_s_setprio(0);

        asm volatile("" ::: "memory");
        __builtin_amdgcn_s_barrier();          // all waves done reading buf bb
        if (it + 2 < iters) {
            STAGE(it + 2, bb);                 // overwrite just-freed buffer
            asm volatile("s_waitcnt vmcnt(8)" ::: "memory");  // tile it+1 landed
            asm volatile("" ::: "memory");
            __builtin_amdgcn_s_barrier();      // visibility of tile it+1
        } else if (it + 1 < iters) {
            asm volatile("s_waitcnt vmcnt(0)" ::: "memory");
            __builtin_amdgcn_s_barrier();
        }
    }

    // ---- epilogue (all q-column-local); partials normalized per split ----
    const int nq0 = n0 + wave * 64 + l31;
    const int nq1 = nq0 + 32;
    const int rbase = 4 * hi;
    float inv0 = 1.0f / lsum0, inv1 = 1.0f / lsum1;
    if (lg2S == 0) {
        #pragma unroll
        for (int ct = 0; ct < 4; ++ct)
            #pragma unroll
            for (int rg = 0; rg < 16; ++rg) {
                int c = ct * 32 + (rg & 3) + ((rg >> 2) << 3) + rbase;
                out[(size_t)(b * NC + c) * NN + nq0] = o0[ct][rg] * inv0;
                out[(size_t)(b * NC + c) * NN + nq1] = o1[ct][rg] * inv1;
            }
    } else {
        if (hi == 0) {
            statM[(sp * NB + b) * NN + nq0] = mrun0;
            statL[(sp * NB + b) * NN + nq0] = lsum0;
            statM[(sp * NB + b) * NN + nq1] = mrun1;
            statL[(sp * NB + b) * NN + nq1] = lsum1;
        }
        const size_t pbase = (size_t)sp * ((size_t)NB * NC * NN) + (size_t)b * NC * NN;
        #pragma unroll
        for (int ct = 0; ct < 4; ++ct)
            #pragma unroll
            for (int rg = 0; rg < 16; ++rg) {
                int c = ct * 32 + (rg & 3) + ((rg >> 2) << 3) + rbase;
                parts[pbase + (size_t)c * NN + nq0] = f2h_u(o0[ct][rg] * inv0);
                parts[pbase + (size_t)c * NN + nq1] = f2h_u(o1[ct][rg] * inv1);
            }
    }
}

// ---------------------------------------------------------------------------
// Kernel 3: merge S normalized partials. grid NB*64, block 256.
// ---------------------------------------------------------------------------
template <int SS>
__device__ __forceinline__ void merge_body(
    const u16* __restrict__ parts,
    const float* __restrict__ statM, const float* __restrict__ statL,
    float* __restrict__ out, int b, int n, int cg)
{
    const size_t PST = (size_t)NB * NC * NN;
    float w0[SS], w1[SS];
    {
        float M0 = -3.0e38f, M1 = -3.0e38f;
        #pragma unroll
        for (int sp = 0; sp < SS; ++sp) {
            w0[sp] = statM[(sp * NB + b) * NN + n];
            w1[sp] = statM[(sp * NB + b) * NN + n + 1];
            M0 = fmaxf(M0, w0[sp]); M1 = fmaxf(M1, w1[sp]);
        }
        float d0 = 0.f, d1 = 0.f;
        #pragma unroll
        for (int sp = 0; sp < SS; ++sp) {
            float e0 = __expf(w0[sp] - M0) * statL[(sp * NB + b) * NN + n];
            float e1 = __expf(w1[sp] - M1) * statL[(sp * NB + b) * NN + n + 1];
            w0[sp] = e0; w1[sp] = e1; d0 += e0; d1 += e1;
        }
        d0 = 1.f / d0; d1 = 1.f / d1;
        #pragma unroll
        for (int sp = 0; sp < SS; ++sp) { w0[sp] *= d0; w1[sp] *= d1; }
    }

    #pragma unroll 4
    for (int i = 0; i < 16; ++i) {
        int c = cg * 16 + i;
        size_t e = (size_t)(b * NC + c) * NN + n;
        float a0 = 0.f, a1 = 0.f;
        #pragma unroll
        for (int sp = 0; sp < SS; ++sp) {
            u32 v = *(const u32*)(parts + sp * PST + e);
            a0 += w0[sp] * h2f_u(v);
            a1 += w1[sp] * h2f_u(v >> 16);
        }
        float2 r; r.x = a0; r.y = a1;
        *(float2*)(out + e) = r;
    }
}

__global__ __launch_bounds__(256) void merge_kernel(
    const u16* __restrict__ parts,
    const float* __restrict__ statM, const float* __restrict__ statL,
    float* __restrict__ out, int S)
{
    const int b  = blockIdx.x >> 6;
    const int nb = (blockIdx.x & 63) << 6;
    const int t  = threadIdx.x;
    const int n  = nb + ((t & 31) << 1);
    const int cg = t >> 5;
    if (S == 8) merge_body<8>(parts, statM, statL, out, b, n, cg);
    else        merge_body<4>(parts, statM, statL, out, b, n, cg);
}

extern "C" void kernel_launch(void* const* d_in, const int* in_sizes, int n_in,
                              void* d_out, int out_size, void* d_ws, size_t ws_size,
                              hipStream_t stream)
{
    const float* x  = (const float*)d_in[0];
    const float* wq = (const float*)d_in[1];
    const float* bq = (const float*)d_in[2];
    const float* wk = (const float*)d_in[3];
    const float* bk = (const float*)d_in[4];
    const float* wv = (const float*)d_in[5];
    const float* bv = (const float*)d_in[6];

    const size_t TE = (size_t)NB * NN * NC;              // 2M elems / tensor
    _Float16* Qb = (_Float16*)d_ws;
    _Float16* Kb = Qb + TE;
    _Float16* Vb = Kb + TE;
    char* base = (char*)d_ws;
    const size_t statOff = 3 * TE * 2;                   // 12 MB
    const size_t statSz  = (size_t)8 * NB * NN * 4;      // 512 KB (up to S=8)
    float* statM = (float*)(base + statOff);
    float* statL = (float*)(base + statOff + statSz);
    const size_t pOff = statOff + 2 * statSz;            // 13 MB
    u16* parts = (u16*)(base + pOff);

    int lg2S;
    if (ws_size >= pOff + 8 * TE * 2)       lg2S = 3;    // S=8 (+32 MB)
    else if (ws_size >= pOff + 4 * TE * 2)  lg2S = 2;    // S=4 (+16 MB)
    else                                    lg2S = 0;    // S=1

    qkv_proj_kernel<<<dim3(256), dim3(512), 0, stream>>>(x, wq, bq, wk, bk, wv, bv, Qb, Kb, Vb);
    attn_kernel<<<dim3(64 << lg2S), dim3(256), 0, stream>>>(Qb, Kb, Vb, (float*)d_out,
                                                            parts, statM, statL, lg2S);
    if (lg2S > 0)
        merge_kernel<<<dim3(NB * 64), dim3(256), 0, stream>>>(parts, statM, statL,
                                                              (float*)d_out, 1 << lg2S);
}

// Round 9
// 102.349 us; speedup vs baseline: 1.6975x; 1.6975x over previous
//
#include <hip/hip_runtime.h>

typedef _Float16 half8 __attribute__((ext_vector_type(8)));
typedef __fp16 fp16x2 __attribute__((ext_vector_type(2)));
typedef float f32x4 __attribute__((ext_vector_type(4)));
typedef float f32x16 __attribute__((ext_vector_type(16)));
typedef unsigned int u32;
typedef unsigned short u16;

#define NB 4
#define NC 128
#define NN 4096
#define THR 8.0f

__device__ __forceinline__ void gload16(const void* g, void* l) {
    __builtin_amdgcn_global_load_lds(
        (const __attribute__((address_space(1))) u32*)g,
        (__attribute__((address_space(3))) u32*)l, 16, 0, 0);
}
__device__ __forceinline__ float h2f_u(u32 u) {
    u16 us = (u16)u;
    _Float16 h;
    __builtin_memcpy(&h, &us, 2);
    return (float)h;
}
__device__ __forceinline__ u16 f2h_u(float f) {
    _Float16 h = (_Float16)f;
    u16 us;
    __builtin_memcpy(&us, &h, 2);
    return us;
}
__device__ __forceinline__ float exp2_fast(float x) {
#if __has_builtin(__builtin_amdgcn_exp2f)
    return __builtin_amdgcn_exp2f(x);
#else
    return exp2f(x);
#endif
}
__device__ __forceinline__ int xs_addr(int c, int n) {
    return ((c << 8) + (n << 2)) ^ (((c >> 3) & 1) << 6);
}

// ---------------------------------------------------------------------------
// Kernel 1: QKV projection via fp16 MFMA (unchanged; works).
// ---------------------------------------------------------------------------
__global__ __launch_bounds__(512, 2) void qkv_proj_kernel(
    const float* __restrict__ x,
    const float* __restrict__ wq, const float* __restrict__ bq,
    const float* __restrict__ wk, const float* __restrict__ bk,
    const float* __restrict__ wv, const float* __restrict__ bv,
    _Float16* __restrict__ Qb, _Float16* __restrict__ Kb, _Float16* __restrict__ Vt)
{
    const int tid  = threadIdx.x;
    const int b    = blockIdx.x >> 6;
    const int n0   = (blockIdx.x & 63) << 6;
    const int lane = tid & 63;
    const int wave = __builtin_amdgcn_readfirstlane(tid >> 6);
    const int l15  = lane & 15, lg = lane >> 4;
    const int obase = wave * 16;

    __shared__ __align__(16) unsigned char xsm[32768];

    #pragma unroll
    for (int kk = 0; kk < 4; ++kk) {
        int g = kk * 512 + tid;
        int c = g >> 4, n4 = (g & 15) << 2;
        *(float4*)(xsm + xs_addr(c, n4)) = *(const float4*)(x + (size_t)(b * NC + c) * NN + n0 + n4);
    }
    __syncthreads();

    half8 bx[4][4];
    #pragma unroll
    for (int ct2 = 0; ct2 < 4; ++ct2) {
        int n = ct2 * 16 + l15;
        #pragma unroll
        for (int kc = 0; kc < 4; ++kc) {
            half8 h;
            #pragma unroll
            for (int j = 0; j < 8; ++j) {
                int c = kc * 32 + lg * 8 + j;
                h[j] = (_Float16)(*(const float*)(xsm + xs_addr(c, n)));
            }
            bx[ct2][kc] = h;
        }
    }

    #pragma unroll 1
    for (int mat = 0; mat < 3; ++mat) {
        const float* __restrict__ W  = (mat == 0) ? wq : ((mat == 1) ? wk : wv);
        const float* __restrict__ bi = (mat == 0) ? bq : ((mat == 1) ? bk : bv);

        half8 aw[4];
        #pragma unroll
        for (int kc = 0; kc < 4; ++kc) {
            const float* wp = W + (size_t)(obase + l15) * NC + kc * 32 + lg * 8;
            float4 w0 = *(const float4*)(wp);
            float4 w1 = *(const float4*)(wp + 4);
            half8 h;
            h[0] = (_Float16)w0.x; h[1] = (_Float16)w0.y; h[2] = (_Float16)w0.z; h[3] = (_Float16)w0.w;
            h[4] = (_Float16)w1.x; h[5] = (_Float16)w1.y; h[6] = (_Float16)w1.z; h[7] = (_Float16)w1.w;
            aw[kc] = h;
        }
        float bvv[4];
        #pragma unroll
        for (int r = 0; r < 4; ++r) bvv[r] = bi[obase + lg * 4 + r];

        f32x4 acc[4];
        #pragma unroll
        for (int ct2 = 0; ct2 < 4; ++ct2) acc[ct2] = (f32x4){0.f, 0.f, 0.f, 0.f};
        #pragma unroll
        for (int kc = 0; kc < 4; ++kc) {
            #pragma unroll
            for (int ct2 = 0; ct2 < 4; ++ct2)
                acc[ct2] = __builtin_amdgcn_mfma_f32_16x16x32_f16(aw[kc], bx[ct2][kc], acc[ct2], 0, 0, 0);
        }

        if (mat < 2) {
            _Float16* dst = (mat == 0) ? Qb : Kb;
            #pragma unroll
            for (int ct2 = 0; ct2 < 4; ++ct2) {
                int n = n0 + ct2 * 16 + l15;
                #pragma unroll
                for (int r = 0; r < 4; ++r)
                    dst[(size_t)(b * NN + n) * NC + obase + lg * 4 + r] = (_Float16)(acc[ct2][r] + bvv[r]);
            }
        } else {
            #pragma unroll
            for (int ct2 = 0; ct2 < 4; ++ct2) {
                int n = n0 + ct2 * 16 + l15;
                #pragma unroll
                for (int r = 0; r < 4; ++r)
                    Vt[(size_t)(b * NC + obase + lg * 4 + r) * NN + n] = (_Float16)(acc[ct2][r] + bvv[r]);
            }
        }
    }
}

// ---------------------------------------------------------------------------
// Kernel 2: flash attention, 32x32x16 MFMA, 64 q-rows per wave (2 q-tiles,
// read:MFMA = 1:2), kv-split S=8 -> 512 blocks. launch_bounds(256,1):
// compiler allocates ~244 VGPR (NO spill; R8's (256,2) forced a 128-cap and
// 500MB of scratch traffic). 244 <= 256 means HW still fits 2 blocks/CU
// (8 waves/CU, LDS 128KB) -> 2 waves/SIMD TLP with halved LDS traffic.
// ---------------------------------------------------------------------------
__global__ __launch_bounds__(256, 1) void attn_kernel(
    const _Float16* __restrict__ Qb, const _Float16* __restrict__ Kb,
    const _Float16* __restrict__ Vt, float* __restrict__ out,
    u16* __restrict__ parts, float* __restrict__ statM, float* __restrict__ statL,
    int lg2S)
{
    const int S = 1 << lg2S;
    const int tid = threadIdx.x;
    const int cpx = gridDim.x >> 3;
    const int lin = (blockIdx.x & 7) * cpx + (blockIdx.x >> 3);
    const int qt   = lin & 15;             // 16 q-tiles of 256
    const int rest = lin >> 4;             // = b * S + sp
    const int sp = rest & (S - 1);
    const int b  = rest >> lg2S;

    const int n0    = qt << 8;             // 256 q per block
    const int kvlen = NN >> lg2S;
    const int kv0   = sp * kvlen;
    const int iters = kvlen >> 6;

    const int lane = tid & 63;
    const int wave = __builtin_amdgcn_readfirstlane(tid >> 6);
    const int l31 = lane & 31, hi = lane >> 5;
    const int s7 = l31 & 7;
    const int s15 = l31 & 15;

    // double buffer: buf = (it&1)<<15. Within buf: K [0,16K), V [16K,32K).
    __shared__ __align__(16) unsigned char smem[65536];

    // ---- staging source offsets (linear LDS dest; inverse of layout map) ----
    int kgo[4], vgo[4], klds[4];
    #pragma unroll
    for (int j = 0; j < 4; ++j) {
        int i = (wave * 4 + j) * 64 + lane;          // chunk 0..1023 (16B units)
        int lam = i >> 4, slot = i & 15;
        int cc = slot ^ (lam & 15);                  // 4-bit XOR swizzle
        int kv = (lam & 51) | ((lam & 4) << 1) | ((lam & 8) >> 1);  // swap bits 2,3
        kgo[j] = kv * NC + cc * 8;
        int c = i >> 3, s2 = i & 7;
        vgo[j] = c * NN + ((s2 ^ (c & 7)) << 3);
        klds[j] = (wave * 4 + j) * 1024;
    }
    const _Float16* Kt0 = Kb + ((size_t)b * NN + kv0) * NC;
    const _Float16* Vt0 = Vt + (size_t)b * NC * NN + kv0;

    // ---- fragment read offsets ----
    int koff[8];
    #pragma unroll
    for (int kc = 0; kc < 8; ++kc) {
        int cc = kc * 2 + hi;
        koff[kc] = l31 * 256 + ((cc ^ s15) << 4);
    }
    int voff[4];
    #pragma unroll
    for (int ks = 0; ks < 4; ++ks) {
        int cc2 = ks * 2 + hi;
        voff[ks] = 16384 + l31 * 128 + ((cc2 ^ s7) << 4);
    }

    auto STAGE = [&](int t, int bb) {
        const _Float16* Kp = Kt0 + (size_t)t * 64 * NC;
        const _Float16* Vp = Vt0 + t * 64;
        #pragma unroll
        for (int j = 0; j < 4; ++j) {
            gload16(Kp + kgo[j], smem + bb + klds[j]);
            gload16(Vp + vgo[j], smem + bb + 16384 + klds[j]);
        }
    };

    // ---- prologue: Q frags first (oldest vmem), then tiles 0 and 1 ----
    half8 aq0[8], aq1[8];
    {
        const _Float16* qp0 = Qb + (size_t)(b * NN + n0 + wave * 64 + l31) * NC + hi * 8;
        const _Float16* qp1 = qp0 + (size_t)32 * NC;
        #pragma unroll
        for (int kc = 0; kc < 8; ++kc) {
            aq0[kc] = *(const half8*)(qp0 + kc * 16);
            aq1[kc] = *(const half8*)(qp1 + kc * 16);
        }
    }
    STAGE(0, 0);
    if (iters > 1) {
        STAGE(1, 32768);
        asm volatile("s_waitcnt vmcnt(8)" ::: "memory");  // q + tile0 landed; tile1 in flight
    } else {
        asm volatile("s_waitcnt vmcnt(0)" ::: "memory");
    }
    __builtin_amdgcn_s_barrier();

    float mrun0 = -3.0e38f, lsum0 = 0.f;
    float mrun1 = -3.0e38f, lsum1 = 0.f;
    f32x16 o0[4], o1[4];
    #pragma unroll
    for (int ct = 0; ct < 4; ++ct)
        #pragma unroll
        for (int r = 0; r < 16; ++r) { o0[ct][r] = 0.f; o1[ct][r] = 0.f; }

    const float L2E = 1.44269504f;

    for (int it = 0; it < iters; ++it) {
        const int bb = (it & 1) << 15;

        // ---- S = K Q^T : each K-frag feeds both q-tiles ----
        f32x16 s00, s01, s10, s11;
        #pragma unroll
        for (int r = 0; r < 16; ++r) { s00[r] = 0.f; s01[r] = 0.f; s10[r] = 0.f; s11[r] = 0.f; }
        __builtin_amdgcn_s_setprio(1);
        #pragma unroll
        for (int kc = 0; kc < 8; ++kc) {
            half8 k0 = *(const half8*)(smem + bb + koff[kc]);
            half8 k1 = *(const half8*)(smem + bb + koff[kc] + 8192);
            s00 = __builtin_amdgcn_mfma_f32_32x32x16_f16(k0, aq0[kc], s00, 0, 0, 0);
            s01 = __builtin_amdgcn_mfma_f32_32x32x16_f16(k1, aq0[kc], s01, 0, 0, 0);
            s10 = __builtin_amdgcn_mfma_f32_32x32x16_f16(k0, aq1[kc], s10, 0, 0, 0);
            s11 = __builtin_amdgcn_mfma_f32_32x32x16_f16(k1, aq1[kc], s11, 0, 0, 0);
        }
        __builtin_amdgcn_s_setprio(0);

        // ---- online softmax, in-lane; defer-rescale THR, per q-tile ----
        float tm0 = fmaxf(s00[0], s00[1]);
        float tm1 = fmaxf(s10[0], s10[1]);
        #pragma unroll
        for (int r = 2; r < 16; r += 2) {
            tm0 = fmaxf(tm0, fmaxf(s00[r], s00[r + 1]));
            tm1 = fmaxf(tm1, fmaxf(s10[r], s10[r + 1]));
        }
        #pragma unroll
        for (int r = 0; r < 16; r += 2) {
            tm0 = fmaxf(tm0, fmaxf(s01[r], s01[r + 1]));
            tm1 = fmaxf(tm1, fmaxf(s11[r], s11[r + 1]));
        }
        tm0 = fmaxf(tm0, __shfl_xor(tm0, 32, 64));
        tm1 = fmaxf(tm1, __shfl_xor(tm1, 32, 64));

        if (__any((tm0 > mrun0 + THR) || (tm1 > mrun1 + THR))) {
            float mn0 = fmaxf(mrun0, tm0);
            float mn1 = fmaxf(mrun1, tm1);
            float sc0 = __expf(mrun0 - mn0);
            float sc1 = __expf(mrun1 - mn1);
            #pragma unroll
            for (int ct = 0; ct < 4; ++ct)
                #pragma unroll
                for (int r = 0; r < 16; ++r) { o0[ct][r] *= sc0; o1[ct][r] *= sc1; }
            lsum0 *= sc0; lsum1 *= sc1;
            mrun0 = mn0; mrun1 = mn1;
        }
        float nm0 = -mrun0 * L2E, nm1 = -mrun1 * L2E;
        float ps0 = 0.f, ps1 = 0.f;
        #pragma unroll
        for (int r = 0; r < 16; ++r) {
            s00[r] = exp2_fast(fmaf(s00[r], L2E, nm0));
            s01[r] = exp2_fast(fmaf(s01[r], L2E, nm0));
            s10[r] = exp2_fast(fmaf(s10[r], L2E, nm1));
            s11[r] = exp2_fast(fmaf(s11[r], L2E, nm1));
            ps0 += s00[r] + s01[r];
            ps1 += s10[r] + s11[r];
        }
        ps0 += __shfl_xor(ps0, 32, 64);
        ps1 += __shfl_xor(ps1, 32, 64);
        lsum0 += ps0; lsum1 += ps1;

        // ---- P -> A-frags, fully in-lane ----
        union H8 { fp16x2 h2[4]; half8 h8; };
        half8 pa0[4], pa1[4];
        {
            H8 a0, a1, a2, a3, b0, b1, b2, b3;
            #pragma unroll
            for (int t = 0; t < 4; ++t) {
                a0.h2[t] = __builtin_amdgcn_cvt_pkrtz(s00[2 * t],     s00[2 * t + 1]);
                a1.h2[t] = __builtin_amdgcn_cvt_pkrtz(s00[8 + 2 * t], s00[9 + 2 * t]);
                a2.h2[t] = __builtin_amdgcn_cvt_pkrtz(s01[2 * t],     s01[2 * t + 1]);
                a3.h2[t] = __builtin_amdgcn_cvt_pkrtz(s01[8 + 2 * t], s01[9 + 2 * t]);
                b0.h2[t] = __builtin_amdgcn_cvt_pkrtz(s10[2 * t],     s10[2 * t + 1]);
                b1.h2[t] = __builtin_amdgcn_cvt_pkrtz(s10[8 + 2 * t], s10[9 + 2 * t]);
                b2.h2[t] = __builtin_amdgcn_cvt_pkrtz(s11[2 * t],     s11[2 * t + 1]);
                b3.h2[t] = __builtin_amdgcn_cvt_pkrtz(s11[8 + 2 * t], s11[9 + 2 * t]);
            }
            pa0[0] = a0.h8; pa0[1] = a1.h8; pa0[2] = a2.h8; pa0[3] = a3.h8;
            pa1[0] = b0.h8; pa1[1] = b1.h8; pa1[2] = b2.h8; pa1[3] = b3.h8;
        }

        // ---- O += V^T P : each V-frag feeds both q-tiles ----
        __builtin_amdgcn_s_setprio(1);
        #pragma unroll
        for (int ks = 0; ks < 4; ++ks) {
            #pragma unroll
            for (int ct = 0; ct < 4; ++ct) {
                half8 vf = *(const half8*)(smem + bb + voff[ks] + ct * 4096);
                o0[ct] = __builtin_amdgcn_mfma_f32_32x32x16_f16(vf, pa0[ks], o0[ct], 0, 0, 0);
                o1[ct] = __builtin_amdgcn_mfma_f32_32x32x16_f16(vf, pa1[ks], o1[ct], 0, 0, 0);
            }
        }
        __builtin_amdgcn_s_setprio(0);

        asm volatile("" ::: "memory");
        __builtin_amdgcn_s_barrier();          // all waves done reading buf bb
        if (it + 2 < iters) {
            STAGE(it + 2, bb);                 // overwrite just-freed buffer
            asm volatile("s_waitcnt vmcnt(8)" ::: "memory");  // tile it+1 landed
            asm volatile("" ::: "memory");
            __builtin_amdgcn_s_barrier();      // visibility of tile it+1
        } else if (it + 1 < iters) {
            asm volatile("s_waitcnt vmcnt(0)" ::: "memory");
            __builtin_amdgcn_s_barrier();
        }
    }

    // ---- epilogue (all q-column-local); partials normalized per split ----
    const int nq0 = n0 + wave * 64 + l31;
    const int nq1 = nq0 + 32;
    const int rbase = 4 * hi;
    float inv0 = 1.0f / lsum0, inv1 = 1.0f / lsum1;
    if (lg2S == 0) {
        #pragma unroll
        for (int ct = 0; ct < 4; ++ct)
            #pragma unroll
            for (int rg = 0; rg < 16; ++rg) {
                int c = ct * 32 + (rg & 3) + ((rg >> 2) << 3) + rbase;
                out[(size_t)(b * NC + c) * NN + nq0] = o0[ct][rg] * inv0;
                out[(size_t)(b * NC + c) * NN + nq1] = o1[ct][rg] * inv1;
            }
    } else {
        if (hi == 0) {
            statM[(sp * NB + b) * NN + nq0] = mrun0;
            statL[(sp * NB + b) * NN + nq0] = lsum0;
            statM[(sp * NB + b) * NN + nq1] = mrun1;
            statL[(sp * NB + b) * NN + nq1] = lsum1;
        }
        const size_t pbase = (size_t)sp * ((size_t)NB * NC * NN) + (size_t)b * NC * NN;
        #pragma unroll
        for (int ct = 0; ct < 4; ++ct)
            #pragma unroll
            for (int rg = 0; rg < 16; ++rg) {
                int c = ct * 32 + (rg & 3) + ((rg >> 2) << 3) + rbase;
                parts[pbase + (size_t)c * NN + nq0] = f2h_u(o0[ct][rg] * inv0);
                parts[pbase + (size_t)c * NN + nq1] = f2h_u(o1[ct][rg] * inv1);
            }
    }
}

// ---------------------------------------------------------------------------
// Kernel 3: merge S normalized partials. grid NB*64, block 256.
// ---------------------------------------------------------------------------
template <int SS>
__device__ __forceinline__ void merge_body(
    const u16* __restrict__ parts,
    const float* __restrict__ statM, const float* __restrict__ statL,
    float* __restrict__ out, int b, int n, int cg)
{
    const size_t PST = (size_t)NB * NC * NN;
    float w0[SS], w1[SS];
    {
        float M0 = -3.0e38f, M1 = -3.0e38f;
        #pragma unroll
        for (int sp = 0; sp < SS; ++sp) {
            w0[sp] = statM[(sp * NB + b) * NN + n];
            w1[sp] = statM[(sp * NB + b) * NN + n + 1];
            M0 = fmaxf(M0, w0[sp]); M1 = fmaxf(M1, w1[sp]);
        }
        float d0 = 0.f, d1 = 0.f;
        #pragma unroll
        for (int sp = 0; sp < SS; ++sp) {
            float e0 = __expf(w0[sp] - M0) * statL[(sp * NB + b) * NN + n];
            float e1 = __expf(w1[sp] - M1) * statL[(sp * NB + b) * NN + n + 1];
            w0[sp] = e0; w1[sp] = e1; d0 += e0; d1 += e1;
        }
        d0 = 1.f / d0; d1 = 1.f / d1;
        #pragma unroll
        for (int sp = 0; sp < SS; ++sp) { w0[sp] *= d0; w1[sp] *= d1; }
    }

    #pragma unroll 4
    for (int i = 0; i < 16; ++i) {
        int c = cg * 16 + i;
        size_t e = (size_t)(b * NC + c) * NN + n;
        float a0 = 0.f, a1 = 0.f;
        #pragma unroll
        for (int sp = 0; sp < SS; ++sp) {
            u32 v = *(const u32*)(parts + sp * PST + e);
            a0 += w0[sp] * h2f_u(v);
            a1 += w1[sp] * h2f_u(v >> 16);
        }
        float2 r; r.x = a0; r.y = a1;
        *(float2*)(out + e) = r;
    }
}

__global__ __launch_bounds__(256) void merge_kernel(
    const u16* __restrict__ parts,
    const float* __restrict__ statM, const float* __restrict__ statL,
    float* __restrict__ out, int S)
{
    const int b  = blockIdx.x >> 6;
    const int nb = (blockIdx.x & 63) << 6;
    const int t  = threadIdx.x;
    const int n  = nb + ((t & 31) << 1);
    const int cg = t >> 5;
    if (S == 8) merge_body<8>(parts, statM, statL, out, b, n, cg);
    else        merge_body<4>(parts, statM, statL, out, b, n, cg);
}

extern "C" void kernel_launch(void* const* d_in, const int* in_sizes, int n_in,
                              void* d_out, int out_size, void* d_ws, size_t ws_size,
                              hipStream_t stream)
{
    const float* x  = (const float*)d_in[0];
    const float* wq = (const float*)d_in[1];
    const float* bq = (const float*)d_in[2];
    const float* wk = (const float*)d_in[3];
    const float* bk = (const float*)d_in[4];
    const float* wv = (const float*)d_in[5];
    const float* bv = (const float*)d_in[6];

    const size_t TE = (size_t)NB * NN * NC;              // 2M elems / tensor
    _Float16* Qb = (_Float16*)d_ws;
    _Float16* Kb = Qb + TE;
    _Float16* Vb = Kb + TE;
    char* base = (char*)d_ws;
    const size_t statOff = 3 * TE * 2;                   // 12 MB
    const size_t statSz  = (size_t)8 * NB * NN * 4;      // 512 KB (up to S=8)
    float* statM = (float*)(base + statOff);
    float* statL = (float*)(base + statOff + statSz);
    const size_t pOff = statOff + 2 * statSz;            // 13 MB
    u16* parts = (u16*)(base + pOff);

    int lg2S;
    if (ws_size >= pOff + 8 * TE * 2)       lg2S = 3;    // S=8 (+32 MB)
    else if (ws_size >= pOff + 4 * TE * 2)  lg2S = 2;    // S=4 (+16 MB)
    else                                    lg2S = 0;    // S=1

    qkv_proj_kernel<<<dim3(256), dim3(512), 0, stream>>>(x, wq, bq, wk, bk, wv, bv, Qb, Kb, Vb);
    attn_kernel<<<dim3(64 << lg2S), dim3(256), 0, stream>>>(Qb, Kb, Vb, (float*)d_out,
                                                            parts, statM, statL, lg2S);
    if (lg2S > 0)
        merge_kernel<<<dim3(NB * 64), dim3(256), 0, stream>>>(parts, statM, statL,
                                                              (float*)d_out, 1 << lg2S);
}

// Round 10
// 70.607 us; speedup vs baseline: 2.4606x; 1.4496x over previous
//
#include <hip/hip_runtime.h>

typedef _Float16 half8 __attribute__((ext_vector_type(8)));
typedef __fp16 fp16x2 __attribute__((ext_vector_type(2)));
typedef float f32x4 __attribute__((ext_vector_type(4)));
typedef float f32x16 __attribute__((ext_vector_type(16)));
typedef unsigned int u32;
typedef unsigned short u16;

#define NB 4
#define NC 128
#define NN 4096
#define THR 8.0f

__device__ __forceinline__ void gload16(const void* g, void* l) {
    __builtin_amdgcn_global_load_lds(
        (const __attribute__((address_space(1))) u32*)g,
        (__attribute__((address_space(3))) u32*)l, 16, 0, 0);
}
__device__ __forceinline__ float h2f_u(u32 u) {
    u16 us = (u16)u;
    _Float16 h;
    __builtin_memcpy(&h, &us, 2);
    return (float)h;
}
__device__ __forceinline__ u16 f2h_u(float f) {
    _Float16 h = (_Float16)f;
    u16 us;
    __builtin_memcpy(&us, &h, 2);
    return us;
}
__device__ __forceinline__ float exp2_fast(float x) {
#if __has_builtin(__builtin_amdgcn_exp2f)
    return __builtin_amdgcn_exp2f(x);
#else
    return exp2f(x);
#endif
}
__device__ __forceinline__ int xs_addr(int c, int n) {
    return ((c << 8) + (n << 2)) ^ (((c >> 3) & 1) << 6);
}

// ---------------------------------------------------------------------------
// Kernel 1: QKV projection via fp16 MFMA. Q/K outputs bounced through LDS so
// global stores are coalesced 32B/thread (old path: 2B at 256B stride = ~8x
// write amplification, ~10us). V keeps direct 32B-run stores.
// ---------------------------------------------------------------------------
__global__ __launch_bounds__(512, 2) void qkv_proj_kernel(
    const float* __restrict__ x,
    const float* __restrict__ wq, const float* __restrict__ bq,
    const float* __restrict__ wk, const float* __restrict__ bk,
    const float* __restrict__ wv, const float* __restrict__ bv,
    _Float16* __restrict__ Qb, _Float16* __restrict__ Kb, _Float16* __restrict__ Vt)
{
    const int tid  = threadIdx.x;
    const int b    = blockIdx.x >> 6;
    const int n0   = (blockIdx.x & 63) << 6;
    const int lane = tid & 63;
    const int wave = __builtin_amdgcn_readfirstlane(tid >> 6);
    const int l15  = lane & 15, lg = lane >> 4;
    const int obase = wave * 16;

    __shared__ __align__(16) unsigned char xsm[32768];

    #pragma unroll
    for (int kk = 0; kk < 4; ++kk) {
        int g = kk * 512 + tid;
        int c = g >> 4, n4 = (g & 15) << 2;
        *(float4*)(xsm + xs_addr(c, n4)) = *(const float4*)(x + (size_t)(b * NC + c) * NN + n0 + n4);
    }
    __syncthreads();

    half8 bx[4][4];
    #pragma unroll
    for (int ct2 = 0; ct2 < 4; ++ct2) {
        int n = ct2 * 16 + l15;
        #pragma unroll
        for (int kc = 0; kc < 4; ++kc) {
            half8 h;
            #pragma unroll
            for (int j = 0; j < 8; ++j) {
                int c = kc * 32 + lg * 8 + j;
                h[j] = (_Float16)(*(const float*)(xsm + xs_addr(c, n)));
            }
            bx[ct2][kc] = h;
        }
    }
    __syncthreads();                       // xsm free for output bounce

    #pragma unroll 1
    for (int mat = 0; mat < 3; ++mat) {
        const float* __restrict__ W  = (mat == 0) ? wq : ((mat == 1) ? wk : wv);
        const float* __restrict__ bi = (mat == 0) ? bq : ((mat == 1) ? bk : bv);

        half8 aw[4];
        #pragma unroll
        for (int kc = 0; kc < 4; ++kc) {
            const float* wp = W + (size_t)(obase + l15) * NC + kc * 32 + lg * 8;
            float4 w0 = *(const float4*)(wp);
            float4 w1 = *(const float4*)(wp + 4);
            half8 h;
            h[0] = (_Float16)w0.x; h[1] = (_Float16)w0.y; h[2] = (_Float16)w0.z; h[3] = (_Float16)w0.w;
            h[4] = (_Float16)w1.x; h[5] = (_Float16)w1.y; h[6] = (_Float16)w1.z; h[7] = (_Float16)w1.w;
            aw[kc] = h;
        }
        float bvv[4];
        #pragma unroll
        for (int r = 0; r < 4; ++r) bvv[r] = bi[obase + lg * 4 + r];

        f32x4 acc[4];
        #pragma unroll
        for (int ct2 = 0; ct2 < 4; ++ct2) acc[ct2] = (f32x4){0.f, 0.f, 0.f, 0.f};
        #pragma unroll
        for (int kc = 0; kc < 4; ++kc) {
            #pragma unroll
            for (int ct2 = 0; ct2 < 4; ++ct2)
                acc[ct2] = __builtin_amdgcn_mfma_f32_16x16x32_f16(aw[kc], bx[ct2][kc], acc[ct2], 0, 0, 0);
        }

        if (mat < 2) {
            // bounce through LDS: tile [64 n][128 c] fp16, swizzled 16B slots
            _Float16* dst = (mat == 0) ? Qb : Kb;
            const int cslot = wave * 2 + (lg >> 1);      // (wave*16+lg*4)>>3
            const int half8off = (lg & 1) * 8;
            #pragma unroll
            for (int ct2 = 0; ct2 < 4; ++ct2) {
                int nl = ct2 * 16 + l15;
                u16 pk[4];
                #pragma unroll
                for (int r = 0; r < 4; ++r) pk[r] = f2h_u(acc[ct2][r] + bvv[r]);
                unsigned long long v;
                __builtin_memcpy(&v, pk, 8);
                *(unsigned long long*)(xsm + nl * 256 + (((cslot ^ (nl & 15)) << 4) | half8off)) = v;
            }
            __syncthreads();
            {
                const int nl = tid >> 3;
                const int s2 = (tid & 7) << 1;
                uint4 v0 = *(const uint4*)(xsm + nl * 256 + ((s2 ^ (nl & 15)) << 4));
                uint4 v1 = *(const uint4*)(xsm + nl * 256 + (((s2 + 1) ^ (nl & 15)) << 4));
                _Float16* dp = dst + (size_t)(b * NN + n0 + nl) * NC + s2 * 8;
                *(uint4*)(dp)     = v0;
                *(uint4*)(dp + 8) = v1;
            }
            __syncthreads();
        } else {
            #pragma unroll
            for (int ct2 = 0; ct2 < 4; ++ct2) {
                int n = n0 + ct2 * 16 + l15;
                #pragma unroll
                for (int r = 0; r < 4; ++r)
                    Vt[(size_t)(b * NC + obase + lg * 4 + r) * NN + n] = (_Float16)(acc[ct2][r] + bvv[r]);
            }
        }
    }
}

// ---------------------------------------------------------------------------
// Kernel 2: flash attention (R5 structure, 51.5us proven): 32x32x16 MFMA,
// 32 q/wave, 128 q/block, kv-split S=4, double-buffered LDS + counted vmcnt
// + raw s_barrier, VGPR ~100 -> 2 blocks/CU. NEW: 4-bit K XOR swizzle
// (R9-verified, conflicts -75%). Normalized fp16 partials.
// ---------------------------------------------------------------------------
__global__ __launch_bounds__(256, 2) void attn_kernel(
    const _Float16* __restrict__ Qb, const _Float16* __restrict__ Kb,
    const _Float16* __restrict__ Vt, float* __restrict__ out,
    u16* __restrict__ parts, float* __restrict__ statM, float* __restrict__ statL,
    int lg2S)
{
    const int S = 1 << lg2S;
    const int tid = threadIdx.x;
    const int cpx = gridDim.x >> 3;
    const int lin = (blockIdx.x & 7) * cpx + (blockIdx.x >> 3);
    const int qt   = lin & 31;             // 32 q-tiles of 128
    const int rest = lin >> 5;             // = b * S + sp
    const int sp = rest & (S - 1);
    const int b  = rest >> lg2S;

    const int n0    = qt << 7;             // 128 q per block
    const int kvlen = NN >> lg2S;
    const int kv0   = sp * kvlen;
    const int iters = kvlen >> 6;

    const int lane = tid & 63;
    const int wave = __builtin_amdgcn_readfirstlane(tid >> 6);
    const int l31 = lane & 31, hi = lane >> 5;
    const int s7 = l31 & 7;
    const int s15 = l31 & 15;

    // double buffer: buf = (it&1)<<15. Within buf: K [0,16K), V [16K,32K).
    __shared__ __align__(16) unsigned char smem[65536];

    // ---- staging source offsets (linear LDS dest; inverse of layout map) ----
    int kgo[4], vgo[4], klds[4];
    #pragma unroll
    for (int j = 0; j < 4; ++j) {
        int i = (wave * 4 + j) * 64 + lane;          // chunk 0..1023 (16B units)
        int lam = i >> 4, slot = i & 15;
        int cc = slot ^ (lam & 15);                  // 4-bit XOR swizzle
        int kv = (lam & 51) | ((lam & 4) << 1) | ((lam & 8) >> 1);  // swap bits 2,3
        kgo[j] = kv * NC + cc * 8;
        int c = i >> 3, s2 = i & 7;
        vgo[j] = c * NN + ((s2 ^ (c & 7)) << 3);
        klds[j] = (wave * 4 + j) * 1024;
    }
    const _Float16* Kt0 = Kb + ((size_t)b * NN + kv0) * NC;
    const _Float16* Vt0 = Vt + (size_t)b * NC * NN + kv0;

    // ---- fragment read offsets ----
    int koff[8];
    #pragma unroll
    for (int kc = 0; kc < 8; ++kc) {
        int cc = kc * 2 + hi;
        koff[kc] = l31 * 256 + ((cc ^ s15) << 4);
    }
    int voff[4];
    #pragma unroll
    for (int ks = 0; ks < 4; ++ks) {
        int cc2 = ks * 2 + hi;
        voff[ks] = 16384 + l31 * 128 + ((cc2 ^ s7) << 4);
    }

    auto STAGE = [&](int t, int bb) {
        const _Float16* Kp = Kt0 + (size_t)t * 64 * NC;
        const _Float16* Vp = Vt0 + t * 64;
        #pragma unroll
        for (int j = 0; j < 4; ++j) {
            gload16(Kp + kgo[j], smem + bb + klds[j]);
            gload16(Vp + vgo[j], smem + bb + 16384 + klds[j]);
        }
    };

    // ---- prologue: Q frags first (oldest vmem), then tiles 0 and 1 ----
    half8 aq[8];
    {
        const _Float16* qp = Qb + (size_t)(b * NN + n0 + wave * 32 + l31) * NC + hi * 8;
        #pragma unroll
        for (int kc = 0; kc < 8; ++kc) aq[kc] = *(const half8*)(qp + kc * 16);
    }
    STAGE(0, 0);
    if (iters > 1) {
        STAGE(1, 32768);
        asm volatile("s_waitcnt vmcnt(8)" ::: "memory");  // q + tile0 landed; tile1 in flight
    } else {
        asm volatile("s_waitcnt vmcnt(0)" ::: "memory");
    }
    __builtin_amdgcn_s_barrier();

    float mrun = -3.0e38f, lsum = 0.f;
    f32x16 o[4];
    #pragma unroll
    for (int ct = 0; ct < 4; ++ct)
        #pragma unroll
        for (int r = 0; r < 16; ++r) o[ct][r] = 0.f;

    const float L2E = 1.44269504f;

    for (int it = 0; it < iters; ++it) {
        const int bb = (it & 1) << 15;

        // ---- S = K Q^T : D[lds-row][q=l31] ----
        f32x16 s0, s1;
        #pragma unroll
        for (int r = 0; r < 16; ++r) { s0[r] = 0.f; s1[r] = 0.f; }
        __builtin_amdgcn_s_setprio(1);
        #pragma unroll
        for (int kc = 0; kc < 8; ++kc) {
            half8 k0 = *(const half8*)(smem + bb + koff[kc]);
            half8 k1 = *(const half8*)(smem + bb + koff[kc] + 8192);
            s0 = __builtin_amdgcn_mfma_f32_32x32x16_f16(k0, aq[kc], s0, 0, 0, 0);
            s1 = __builtin_amdgcn_mfma_f32_32x32x16_f16(k1, aq[kc], s1, 0, 0, 0);
        }
        __builtin_amdgcn_s_setprio(0);

        // ---- online softmax, in-lane for q = l31; defer-rescale THR ----
        float tm = fmaxf(s0[0], s0[1]);
        #pragma unroll
        for (int r = 2; r < 16; r += 2) tm = fmaxf(tm, fmaxf(s0[r], s0[r + 1]));
        #pragma unroll
        for (int r = 0; r < 16; r += 2) tm = fmaxf(tm, fmaxf(s1[r], s1[r + 1]));
        tm = fmaxf(tm, __shfl_xor(tm, 32, 64));

        if (__any(tm > mrun + THR)) {
            float mnew = fmaxf(mrun, tm);
            float sc = __expf(mrun - mnew);    // first iter: exp(-inf) = 0
            #pragma unroll
            for (int ct = 0; ct < 4; ++ct)
                #pragma unroll
                for (int r = 0; r < 16; ++r) o[ct][r] *= sc;
            lsum *= sc;
            mrun = mnew;
        }
        float nm = -mrun * L2E;
        float psum = 0.f;
        #pragma unroll
        for (int r = 0; r < 16; ++r) {
            s0[r] = exp2_fast(fmaf(s0[r], L2E, nm));
            s1[r] = exp2_fast(fmaf(s1[r], L2E, nm));
            psum += s0[r] + s1[r];
        }
        psum += __shfl_xor(psum, 32, 64);
        lsum += psum;

        // ---- P -> A-frags, fully in-lane ----
        union H8 { fp16x2 h2[4]; half8 h8; };
        half8 pa[4];
        {
            H8 u0, u1, u2, u3;
            #pragma unroll
            for (int t = 0; t < 4; ++t) {
                u0.h2[t] = __builtin_amdgcn_cvt_pkrtz(s0[2 * t],     s0[2 * t + 1]);
                u1.h2[t] = __builtin_amdgcn_cvt_pkrtz(s0[8 + 2 * t], s0[9 + 2 * t]);
                u2.h2[t] = __builtin_amdgcn_cvt_pkrtz(s1[2 * t],     s1[2 * t + 1]);
                u3.h2[t] = __builtin_amdgcn_cvt_pkrtz(s1[8 + 2 * t], s1[9 + 2 * t]);
            }
            pa[0] = u0.h8; pa[1] = u1.h8; pa[2] = u2.h8; pa[3] = u3.h8;
        }

        // ---- O += V^T P : D[c][q=l31] ----
        __builtin_amdgcn_s_setprio(1);
        #pragma unroll
        for (int ks = 0; ks < 4; ++ks) {
            #pragma unroll
            for (int ct = 0; ct < 4; ++ct) {
                half8 vf = *(const half8*)(smem + bb + voff[ks] + ct * 4096);
                o[ct] = __builtin_amdgcn_mfma_f32_32x32x16_f16(vf, pa[ks], o[ct], 0, 0, 0);
            }
        }
        __builtin_amdgcn_s_setprio(0);

        asm volatile("" ::: "memory");
        __builtin_amdgcn_s_barrier();          // all waves done reading buf bb
        if (it + 2 < iters) {
            STAGE(it + 2, bb);                 // overwrite just-freed buffer
            asm volatile("s_waitcnt vmcnt(8)" ::: "memory");  // tile it+1 landed
            asm volatile("" ::: "memory");
            __builtin_amdgcn_s_barrier();      // visibility of tile it+1
        } else if (it + 1 < iters) {
            asm volatile("s_waitcnt vmcnt(0)" ::: "memory");
            __builtin_amdgcn_s_barrier();
        }
    }

    // ---- epilogue (all q-column-local); partials normalized per split ----
    const int nq = n0 + wave * 32 + l31;
    const int rbase = 4 * hi;
    float inv = 1.0f / lsum;
    if (lg2S == 0) {
        #pragma unroll
        for (int ct = 0; ct < 4; ++ct)
            #pragma unroll
            for (int rg = 0; rg < 16; ++rg) {
                int c = ct * 32 + (rg & 3) + ((rg >> 2) << 3) + rbase;
                out[(size_t)(b * NC + c) * NN + nq] = o[ct][rg] * inv;
            }
    } else {
        if (hi == 0) {
            statM[(sp * NB + b) * NN + nq] = mrun;
            statL[(sp * NB + b) * NN + nq] = lsum;
        }
        const size_t pbase = (size_t)sp * ((size_t)NB * NC * NN) + (size_t)b * NC * NN + nq;
        #pragma unroll
        for (int ct = 0; ct < 4; ++ct)
            #pragma unroll
            for (int rg = 0; rg < 16; ++rg) {
                int c = ct * 32 + (rg & 3) + ((rg >> 2) << 3) + rbase;
                parts[pbase + (size_t)c * NN] = f2h_u(o[ct][rg] * inv);
            }
    }
}

// ---------------------------------------------------------------------------
// Kernel 3: merge 4 normalized partials. grid NB*64, block 256.
// ---------------------------------------------------------------------------
__global__ __launch_bounds__(256) void merge_kernel(
    const u16* __restrict__ parts,
    const float* __restrict__ statM, const float* __restrict__ statL,
    float* __restrict__ out)
{
    const int b  = blockIdx.x >> 6;
    const int nb = (blockIdx.x & 63) << 6;
    const int t  = threadIdx.x;
    const int n  = nb + ((t & 31) << 1);
    const int cg = t >> 5;
    const size_t PST = (size_t)NB * NC * NN;

    float w0[4], w1[4];
    {
        float M0 = -3.0e38f, M1 = -3.0e38f;
        #pragma unroll
        for (int sp = 0; sp < 4; ++sp) {
            w0[sp] = statM[(sp * NB + b) * NN + n];
            w1[sp] = statM[(sp * NB + b) * NN + n + 1];
            M0 = fmaxf(M0, w0[sp]); M1 = fmaxf(M1, w1[sp]);
        }
        float d0 = 0.f, d1 = 0.f;
        #pragma unroll
        for (int sp = 0; sp < 4; ++sp) {
            float e0 = __expf(w0[sp] - M0) * statL[(sp * NB + b) * NN + n];
            float e1 = __expf(w1[sp] - M1) * statL[(sp * NB + b) * NN + n + 1];
            w0[sp] = e0; w1[sp] = e1; d0 += e0; d1 += e1;
        }
        d0 = 1.f / d0; d1 = 1.f / d1;
        #pragma unroll
        for (int sp = 0; sp < 4; ++sp) { w0[sp] *= d0; w1[sp] *= d1; }
    }

    #pragma unroll 4
    for (int i = 0; i < 16; ++i) {
        int c = cg * 16 + i;
        size_t e = (size_t)(b * NC + c) * NN + n;
        float a0 = 0.f, a1 = 0.f;
        #pragma unroll
        for (int sp = 0; sp < 4; ++sp) {
            u32 v = *(const u32*)(parts + sp * PST + e);
            a0 += w0[sp] * h2f_u(v);
            a1 += w1[sp] * h2f_u(v >> 16);
        }
        float2 r; r.x = a0; r.y = a1;
        *(float2*)(out + e) = r;
    }
}

extern "C" void kernel_launch(void* const* d_in, const int* in_sizes, int n_in,
                              void* d_out, int out_size, void* d_ws, size_t ws_size,
                              hipStream_t stream)
{
    const float* x  = (const float*)d_in[0];
    const float* wq = (const float*)d_in[1];
    const float* bq = (const float*)d_in[2];
    const float* wk = (const float*)d_in[3];
    const float* bk = (const float*)d_in[4];
    const float* wv = (const float*)d_in[5];
    const float* bv = (const float*)d_in[6];

    const size_t TE = (size_t)NB * NN * NC;              // 2M elems / tensor
    _Float16* Qb = (_Float16*)d_ws;
    _Float16* Kb = Qb + TE;
    _Float16* Vb = Kb + TE;
    char* base = (char*)d_ws;
    const size_t statOff = 3 * TE * 2;                   // 12 MB
    const size_t statSz  = (size_t)4 * NB * NN * 4;      // 256 KB (S=4)
    float* statM = (float*)(base + statOff);
    float* statL = (float*)(base + statOff + statSz);
    const size_t pOff = statOff + 2 * statSz;
    u16* parts = (u16*)(base + pOff);
    const size_t need = pOff + 4 * TE * 2;               // + 16 MB partials

    int lg2S = (ws_size >= need) ? 2 : 0;                // S=4 or fallback S=1

    qkv_proj_kernel<<<dim3(256), dim3(512), 0, stream>>>(x, wq, bq, wk, bk, wv, bv, Qb, Kb, Vb);
    attn_kernel<<<dim3(128 << lg2S), dim3(256), 0, stream>>>(Qb, Kb, Vb, (float*)d_out,
                                                             parts, statM, statL, lg2S);
    if (lg2S > 0)
        merge_kernel<<<dim3(NB * 64), dim3(256), 0, stream>>>(parts, statM, statL, (float*)d_out);
}